// Round 16
// baseline (535.794 us; speedup 1.0000x reference)
//
#include <hip/hip_runtime.h>
#include <hip/hip_bf16.h>
#include <math.h>

#define BB 8
#define CCH 256          // channels
#define NN 2304          // H*W
#define NH 4
#define HDIM 64
#define QKV_ROWS 384
#define BN_EPS 1e-5f
#define NTILES 36        // NN / 64
#define HTILES 18        // NTILES / 2 (key-split halves)
#define NPART 288        // BB * 36 proj blocks contributing per channel
// scale folded into q weights: 1/sqrt(64) * log2(e)  -> attention uses exp2
#define SLOG2E 0.18033688011112042f

typedef short bf16x8 __attribute__((ext_vector_type(8)));
typedef short bf16x4 __attribute__((ext_vector_type(4)));
typedef float f32x4 __attribute__((ext_vector_type(4)));

#if __has_builtin(__builtin_amdgcn_exp2f)
#define EXP2(x) __builtin_amdgcn_exp2f(x)
#else
#define EXP2(x) __expf((x) * 0.6931471805599453f)
#endif

// K=16 bf16 MFMA: A/B = 4 bf16 (2 VGPRs), C/D = 4 f32 (ISA §10).
#define MFMA16(a, b, c) __builtin_amdgcn_mfma_f32_16x16x16bf16_1k(a, b, c, 0, 0, 0)
#define MFMA32(a, b, c) __builtin_amdgcn_mfma_f32_16x16x32_bf16(a, b, c, 0, 0, 0)

__device__ __forceinline__ unsigned bfpair(float a, float b) {
    __hip_bfloat162 h = __float22bfloat162_rn(make_float2(a, b));
    return *(unsigned*)&h;
}
__device__ __forceinline__ unsigned short f2bf(float f) {
    unsigned u = __float_as_uint(f);
    u = (u + 0x7FFFu + ((u >> 16) & 1u)) >> 16;
    return (unsigned short)u;
}
__device__ __forceinline__ bf16x4 pack4(float p0, float p1, float p2, float p3) {
    union { unsigned u[2]; bf16x4 v; } x;
    x.u[0] = bfpair(p0, p1);
    x.u[1] = bfpair(p2, p3);
    return x.v;
}
__device__ __forceinline__ float bf2f(unsigned short s) {
    return __uint_as_float((unsigned)s << 16);
}

// ---------------------------------------------------------------------------
// K0: prep — x-transpose/convert (+bf16 residual copy xb) + weight convert.
// ---------------------------------------------------------------------------
__global__ __launch_bounds__(256) void prep_k(
    const float* __restrict__ x,
    const float* __restrict__ qw, const float* __restrict__ kw,
    const float* __restrict__ vw, const float* __restrict__ pw,
    unsigned short* __restrict__ xT, unsigned short* __restrict__ xb,
    unsigned short* __restrict__ Wb, unsigned short* __restrict__ Pb)
{
    const int bid = blockIdx.x;
    const int tid = threadIdx.x;
    if (bid < 1152) {
        __shared__ float sX[64][65];
        const int b  = bid / 144;
        const int rem = bid - b * 144;
        const int nb = (rem >> 2) * 64;
        const int cb = (rem & 3) * 64;

        #pragma unroll
        for (int u = 0; u < 4; ++u) {
            int c  = (tid >> 4) + 16 * u;
            int n4 = (tid & 15) * 4;
            float4 v = *(const float4*)(x + ((size_t)(b * CCH + cb + c)) * NN + nb + n4);
            sX[c][n4+0] = v.x; sX[c][n4+1] = v.y; sX[c][n4+2] = v.z; sX[c][n4+3] = v.w;
        }
        __syncthreads();

        // xT[b][n][c] (transposed)
        const int n  = tid >> 2;
        const int cg = (tid & 3) * 16;
        unsigned vals[8];
        #pragma unroll
        for (int p = 0; p < 8; ++p)
            vals[p] = bfpair(sX[cg + 2*p][n], sX[cg + 2*p + 1][n]);
        unsigned short* dst = xT + ((size_t)(b * NN + nb + n)) * CCH + cb + cg;
        *(uint4*)dst = make_uint4(vals[0], vals[1], vals[2], vals[3]);
        *(uint4*)(dst + 8) = make_uint4(vals[4], vals[5], vals[6], vals[7]);

        // xb[b][c][n] (same layout as x, bf16) — for bn_apply residual
        #pragma unroll
        for (int it = 0; it < 2; ++it) {
            int flat = tid + 256 * it;      // 0..511
            int row = flat >> 3;            // c local
            int n8  = (flat & 7) * 8;
            unsigned vv[4];
            #pragma unroll
            for (int p = 0; p < 4; ++p)
                vv[p] = bfpair(sX[row][n8 + 2*p], sX[row][n8 + 2*p + 1]);
            *(uint4*)(xb + ((size_t)(b * CCH + cb + row)) * NN + nb + n8) =
                make_uint4(vv[0], vv[1], vv[2], vv[3]);
        }
    } else {
        int idx = (bid - 1152) * 256 + tid;
        if (idx < 98304) {
            int o = idx >> 8, c = idx & 255;
            float v;
            if (o < 256)      v = qw[(size_t)o * CCH + c] * SLOG2E;
            else if (o < 320) v = kw[(size_t)(o - 256) * CCH + c];
            else              v = vw[(size_t)(o - 320) * CCH + c];
            Wb[idx] = f2bf(v);
        } else {
            int j = idx - 98304;
            if (j < 65536) Pb[j] = f2bf(pw[j]);
        }
    }
}

// ---------------------------------------------------------------------------
// K1: qkv MFMA GEMM, K-loop software-pipelined (round-11/13 verified 64x64).
// grid (8 b, 36 ntile, 3 otile), 128 thr (2 waves).
//   Qt[b][n][256] (q pre-scaled), Kt[b][n][64], Vn[b][64][n], all bf16.
// ---------------------------------------------------------------------------
__global__ __launch_bounds__(128) void qkv_mfma_k(
    const unsigned short* __restrict__ Wb, const unsigned short* __restrict__ xT,
    unsigned short* __restrict__ Qt, unsigned short* __restrict__ Kt,
    unsigned short* __restrict__ Vn)
{
    __shared__ unsigned short sE[2][64 * 72];
    const int tid = threadIdx.x;
    const int wave = tid >> 6;
    const int lane = tid & 63;
    const int quad = lane >> 4;
    const int l15  = lane & 15;
    const int b  = blockIdx.x;
    const int nb = blockIdx.y * 64;
    const int mb = blockIdx.z * 128 + wave * 64;

    const unsigned short* Ab = Wb + (size_t)(mb + l15) * CCH + quad * 8;
    const unsigned short* Bb = xT + ((size_t)(b * NN + nb + l15)) * CCH + quad * 8;

    f32x4 C[4][4] = {};
    bf16x8 aA[2][4], bB[2][4];
    #pragma unroll
    for (int i = 0; i < 4; ++i) aA[0][i] = *(const bf16x8*)(Ab + (size_t)(16*i) * CCH);
    #pragma unroll
    for (int j = 0; j < 4; ++j) bB[0][j] = *(const bf16x8*)(Bb + (size_t)(16*j) * CCH);

    #pragma unroll
    for (int kk = 0; kk < 8; ++kk) {
        const int cur = kk & 1;
        if (kk < 7) {
            const int k1 = (kk + 1) * 32;
            #pragma unroll
            for (int i = 0; i < 4; ++i) aA[cur^1][i] = *(const bf16x8*)(Ab + (size_t)(16*i) * CCH + k1);
            #pragma unroll
            for (int j = 0; j < 4; ++j) bB[cur^1][j] = *(const bf16x8*)(Bb + (size_t)(16*j) * CCH + k1);
        }
        #pragma unroll
        for (int i = 0; i < 4; ++i)
            #pragma unroll
            for (int j = 0; j < 4; ++j)
                C[i][j] = MFMA32(aA[cur][i], bB[cur][j], C[i][j]);
    }

    unsigned short* sEw = &sE[wave][0];
    if (mb < 320) {
        // Q or K: transpose to [n][o] rows
        #pragma unroll
        for (int i = 0; i < 4; ++i)
            #pragma unroll
            for (int j = 0; j < 4; ++j) {
                unsigned p01 = bfpair(C[i][j][0], C[i][j][1]);
                unsigned p23 = bfpair(C[i][j][2], C[i][j][3]);
                unsigned short* p = sEw + (16*j + l15) * 72 + 16*i + quad*4;
                *(unsigned*)p = p01;
                *(unsigned*)(p + 2) = p23;
            }
        if (mb < 256) {
            #pragma unroll
            for (int it = 0; it < 8; ++it) {
                int flat = lane + 64 * it;
                int row = flat >> 3;
                int o8  = (flat & 7) * 8;
                uint4 v = *(const uint4*)(sEw + row * 72 + o8);
                *(uint4*)(Qt + ((size_t)(b * NN + nb + row)) * CCH + mb + o8) = v;
            }
        } else {
            #pragma unroll
            for (int it = 0; it < 8; ++it) {
                int flat = lane + 64 * it;
                int row = flat >> 3;
                int o8  = (flat & 7) * 8;
                uint4 v = *(const uint4*)(sEw + row * 72 + o8);
                *(uint4*)(Kt + ((size_t)(b * NN + nb + row)) * 64 + o8) = v;
            }
        }
    } else {
        // V: [d][n] rows
        #pragma unroll
        for (int i = 0; i < 4; ++i)
            #pragma unroll
            for (int j = 0; j < 4; ++j) {
                unsigned p01 = bfpair(C[i][j][0], C[i][j][1]);
                unsigned p23 = bfpair(C[i][j][2], C[i][j][3]);
                unsigned short* p = sEw + (16*i + quad*4) * 72 + 16*j + l15;
                p[0]   = (unsigned short)p01;
                p[72]  = (unsigned short)(p01 >> 16);
                p[144] = (unsigned short)p23;
                p[216] = (unsigned short)(p23 >> 16);
            }
        #pragma unroll
        for (int it = 0; it < 8; ++it) {
            int flat = lane + 64 * it;
            int row = flat >> 3;
            int n8  = (flat & 7) * 8;
            uint4 v = *(const uint4*)(sEw + row * 72 + n8);
            *(uint4*)(Vn + ((size_t)(b * 64 + (mb - 320) + row)) * NN + nb + n8) = v;
        }
    }
}

// ---------------------------------------------------------------------------
// K2: MFMA attention — r12 single-buffer structure at FULL occupancy:
// __launch_bounds__(512, 8). Natural VGPR footprint is exactly 64 (measured
// r12/r13/r15 under a 128 cap), and 512-reg pool / 64 = 8 waves/SIMD; LDS
// 36864 B -> 4 blocks/CU. 32 waves/CU (hardware max) vs 16 before — doubles
// the latency-hiding pool that all six ~80 µs variants lacked.
// 2 heads/block, 512 thr = 8 waves: (hloc = w>>2) x (khalf) x (qslot).
// ---------------------------------------------------------------------------
__global__ __launch_bounds__(512, 8) void attn_k(
    const unsigned short* __restrict__ Qt,  // [B][N][256]
    const unsigned short* __restrict__ Kt,  // [B][N][64]
    const unsigned short* __restrict__ Vn,  // [B][64][N]
    unsigned short* __restrict__ Ao)        // [B][N][256]
{
    __shared__ __align__(16) unsigned short sKV[4 * 64 * 72];   // 36864 B

    const int tid   = threadIdx.x;
    const int wave  = tid >> 6;
    const int lane  = tid & 63;
    const int quad  = lane >> 4;
    const int l15   = lane & 15;
    const int qslot = wave & 1;
    const int kh    = (wave >> 1) & 1;
    const int hloc  = wave >> 2;
    const int qoff  = qslot * 32;
    const int b     = blockIdx.x;
    const int nb    = blockIdx.y * 64;
    const int head  = blockIdx.z * 2 + hloc;

    unsigned short* sKb = sKV + kh * 2 * 4608;
    unsigned short* sVb = sKb + 4608;

    const bf16x4 vone = {(short)0x3F80, (short)0x3F80, (short)0x3F80, (short)0x3F80};

    // Q fragments (B-operand for S^T): B[n=query=l15][k=d=quad*8+j]
    bf16x8 bQ[2][2];
    const unsigned short* QtB = Qt + ((size_t)(b * NN + nb + qoff + l15)) * CCH + head * 64 + quad * 8;
    #pragma unroll
    for (int qt = 0; qt < 2; ++qt)
        #pragma unroll
        for (int s = 0; s < 2; ++s)
            bQ[qt][s] = *(const bf16x8*)(QtB + (size_t)(16*qt) * CCH + s * 32);

    // staging: 512 thr x 1 chunk per buffer (64 rows x 8 chunks = 512)
    const int srow = tid >> 3;
    const int sch8 = (tid & 7) * 8;
    bf16x8 pf[4];
    #pragma unroll
    for (int u = 0; u < 4; ++u) {
        const int keys0 = (u >> 1) * HTILES * 64;
        if ((u & 1) == 0)
            pf[u] = *(const bf16x8*)(Kt + ((size_t)(b * NN + keys0 + srow)) * 64 + sch8);
        else
            pf[u] = *(const bf16x8*)(Vn + ((size_t)(b * 64 + srow)) * NN + keys0 + sch8);
    }

    f32x4 O[4][2] = {};          // O^T[d-tile jd][q-tile qt]
    f32x4 dacc[2] = {};          // softmax denominators via ones-MFMA

    for (int step = 0; step < HTILES; ++step) {
        __syncthreads();
        #pragma unroll
        for (int u = 0; u < 4; ++u)
            *(bf16x8*)(sKV + u * 4608 + srow * 72 + sch8) = pf[u];
        __syncthreads();

        if (step + 1 < HTILES) {
            #pragma unroll
            for (int u = 0; u < 4; ++u) {
                const int keys0 = ((u >> 1) * HTILES + step + 1) * 64;
                if ((u & 1) == 0)
                    pf[u] = *(const bf16x8*)(Kt + ((size_t)(b * NN + keys0 + srow)) * 64 + sch8);
                else
                    pf[u] = *(const bf16x8*)(Vn + ((size_t)(b * 64 + srow)) * NN + keys0 + sch8);
            }
        }

        // S^T[key][q]
        f32x4 C[4][2] = {};
        #pragma unroll
        for (int s = 0; s < 2; ++s)
            #pragma unroll
            for (int kt = 0; kt < 4; ++kt) {
                bf16x8 aK = *(const bf16x8*)(sKb + (16*kt + l15) * 72 + s * 32 + quad * 8);
                C[kt][0] = MFMA32(aK, bQ[0][s], C[kt][0]);
                C[kt][1] = MFMA32(aK, bQ[1][s], C[kt][1]);
            }

        // P^T = exp2(S^T) -> bf16 B-fragments
        bf16x4 bP[4][2];
        #pragma unroll
        for (int kt = 0; kt < 4; ++kt)
            #pragma unroll
            for (int qt = 0; qt < 2; ++qt)
                bP[kt][qt] = pack4(EXP2(C[kt][qt][0]), EXP2(C[kt][qt][1]),
                                   EXP2(C[kt][qt][2]), EXP2(C[kt][qt][3]));

        // denominators on the matrix pipe
        #pragma unroll
        for (int kt = 0; kt < 4; ++kt) {
            dacc[0] = MFMA16(vone, bP[kt][0], dacc[0]);
            dacc[1] = MFMA16(vone, bP[kt][1], dacc[1]);
        }

        // O^T += V . P^T
        #pragma unroll
        for (int jd = 0; jd < 4; ++jd)
            #pragma unroll
            for (int kt = 0; kt < 4; ++kt) {
                bf16x4 aV = *(const bf16x4*)(sVb + (16*jd + l15) * 72 + 16*kt + quad*4);
                O[jd][0] = MFMA16(aV, bP[kt][0], O[jd][0]);
                O[jd][1] = MFMA16(aV, bP[kt][1], O[jd][1]);
            }
    }
    __syncthreads();

    // merge key halves
    float* sc = (float*)sKV;
    const int base = (hloc * 2 + qslot) * 2304 + lane * 36;
    if (kh == 1) {
        #pragma unroll
        for (int jd = 0; jd < 4; ++jd)
            #pragma unroll
            for (int qt = 0; qt < 2; ++qt)
                *(f32x4*)(sc + base + jd * 8 + qt * 4) = O[jd][qt];
        sc[base + 32] = dacc[0][0];
        sc[base + 33] = dacc[1][0];
    }
    __syncthreads();
    float rinv[2] = {0.f, 0.f};
    if (kh == 0) {
        #pragma unroll
        for (int jd = 0; jd < 4; ++jd)
            #pragma unroll
            for (int qt = 0; qt < 2; ++qt)
                O[jd][qt] += *(const f32x4*)(sc + base + jd * 8 + qt * 4);
        rinv[0] = 1.0f / (dacc[0][0] + sc[base + 32]);
        rinv[1] = 1.0f / (dacc[1][0] + sc[base + 33]);
    }
    __syncthreads();

    unsigned short* sT = (unsigned short*)sKV;   // [2 hloc][64 n][72]
    if (kh == 0) {
        #pragma unroll
        for (int qt = 0; qt < 2; ++qt)
            #pragma unroll
            for (int jd = 0; jd < 4; ++jd) {
                unsigned lo = bfpair(O[jd][qt][0] * rinv[qt], O[jd][qt][1] * rinv[qt]);
                unsigned hi = bfpair(O[jd][qt][2] * rinv[qt], O[jd][qt][3] * rinv[qt]);
                *(uint2*)(sT + (hloc * 64 + qoff + 16*qt + l15) * 72 + 16*jd + quad*4) = make_uint2(lo, hi);
            }
    }
    __syncthreads();

    #pragma unroll
    for (int it = 0; it < 2; ++it) {
        int flat = tid + 512 * it;          // 0..1023
        int hh   = flat >> 9;
        int row  = (flat >> 3) & 63;
        int c8   = (flat & 7) * 8;
        uint4 v = *(const uint4*)(sT + (hh * 64 + row) * 72 + c8);
        *(uint4*)(Ao + ((size_t)(b * NN + nb + row)) * CCH + (blockIdx.z * 2 + hh) * 64 + c8) = v;
    }
}

// ---------------------------------------------------------------------------
// K3: proj MFMA GEMM (64x64 pipelined) + per-block BN partials.
// projb[b][c][n] (bf16) = sum_o Pb[c][o]*Ao[b][n][o]+pb[c]
// grid (8 b, 36 ntile, 2 ctile), 128 thr (2 waves).
// ---------------------------------------------------------------------------
__global__ __launch_bounds__(128) void proj_mfma_k(
    const unsigned short* __restrict__ Pb, const unsigned short* __restrict__ Ao,
    const float* __restrict__ pb, unsigned short* __restrict__ projb,
    float* __restrict__ psum, float* __restrict__ psq)
{
    __shared__ unsigned short sE[2][64 * 72];
    const int tid = threadIdx.x;
    const int wave = tid >> 6;
    const int lane = tid & 63;
    const int quad = lane >> 4;
    const int l15  = lane & 15;
    const int b  = blockIdx.x;
    const int nb = blockIdx.y * 64;
    const int mb = blockIdx.z * 128 + wave * 64;
    const int part = b * NTILES + blockIdx.y;   // 0..287

    const unsigned short* Ab = Pb + (size_t)(mb + l15) * CCH + quad * 8;
    const unsigned short* Bb = Ao + ((size_t)(b * NN + nb + l15)) * CCH + quad * 8;

    f32x4 C[4][4] = {};
    bf16x8 aA[2][4], bB[2][4];
    #pragma unroll
    for (int i = 0; i < 4; ++i) aA[0][i] = *(const bf16x8*)(Ab + (size_t)(16*i) * CCH);
    #pragma unroll
    for (int j = 0; j < 4; ++j) bB[0][j] = *(const bf16x8*)(Bb + (size_t)(16*j) * CCH);

    #pragma unroll
    for (int kk = 0; kk < 8; ++kk) {
        const int cur = kk & 1;
        if (kk < 7) {
            const int k1 = (kk + 1) * 32;
            #pragma unroll
            for (int i = 0; i < 4; ++i) aA[cur^1][i] = *(const bf16x8*)(Ab + (size_t)(16*i) * CCH + k1);
            #pragma unroll
            for (int j = 0; j < 4; ++j) bB[cur^1][j] = *(const bf16x8*)(Bb + (size_t)(16*j) * CCH + k1);
        }
        #pragma unroll
        for (int i = 0; i < 4; ++i)
            #pragma unroll
            for (int j = 0; j < 4; ++j)
                C[i][j] = MFMA32(aA[cur][i], bB[cur][j], C[i][j]);
    }

    unsigned short* sEw = &sE[wave][0];
    #pragma unroll
    for (int i = 0; i < 4; ++i) {
        #pragma unroll
        for (int r = 0; r < 4; ++r) {
            const int ch = mb + 16*i + quad*4 + r;
            const float bias = pb[ch];
            float v0 = C[i][0][r] + bias, v1 = C[i][1][r] + bias;
            float v2 = C[i][2][r] + bias, v3 = C[i][3][r] + bias;
            C[i][0][r] = v0; C[i][1][r] = v1; C[i][2][r] = v2; C[i][3][r] = v3;
            float rs = (v0 + v1) + (v2 + v3);
            float rq = (v0*v0 + v1*v1) + (v2*v2 + v3*v3);
            rs += __shfl_xor(rs, 1); rq += __shfl_xor(rq, 1);
            rs += __shfl_xor(rs, 2); rq += __shfl_xor(rq, 2);
            rs += __shfl_xor(rs, 4); rq += __shfl_xor(rq, 4);
            rs += __shfl_xor(rs, 8); rq += __shfl_xor(rq, 8);
            if (l15 == 0) {
                psum[(size_t)ch * NPART + part] = rs;
                psq [(size_t)ch * NPART + part] = rq;
            }
        }
    }

    // bf16 output via LDS transpose: rows = c_local, cols = n
    #pragma unroll
    for (int i = 0; i < 4; ++i)
        #pragma unroll
        for (int j = 0; j < 4; ++j) {
            unsigned p01 = bfpair(C[i][j][0], C[i][j][1]);
            unsigned p23 = bfpair(C[i][j][2], C[i][j][3]);
            unsigned short* p = sEw + (16*i + quad*4) * 72 + 16*j + l15;
            p[0]   = (unsigned short)p01;
            p[72]  = (unsigned short)(p01 >> 16);
            p[144] = (unsigned short)p23;
            p[216] = (unsigned short)(p23 >> 16);
        }
    #pragma unroll
    for (int it = 0; it < 8; ++it) {
        int flat = lane + 64 * it;
        int row = flat >> 3;                // c local
        int n8  = (flat & 7) * 8;
        uint4 v = *(const uint4*)(sEw + row * 72 + n8);
        *(uint4*)(projb + ((size_t)(b * CCH + mb + row)) * NN + nb + n8) = v;
    }
}

// ---------------------------------------------------------------------------
// K4: fused BN finalize + apply. grid (8 b, 256 c), 256 thr.
// out = scale[c]*projb + shift[c] + xb   (projb, xb bf16; out fp32)
// ---------------------------------------------------------------------------
__global__ __launch_bounds__(256) void bn_apply_k(
    const unsigned short* __restrict__ projb, const unsigned short* __restrict__ xb,
    const float* __restrict__ psum, const float* __restrict__ psq,
    const float* __restrict__ gamma, const float* __restrict__ beta,
    float* __restrict__ out)
{
    const int tid = threadIdx.x;
    const int b = blockIdx.x;
    const int c = blockIdx.y;

    float s = 0.f, q = 0.f;
    for (int k = tid; k < NPART; k += 256) {
        s += psum[(size_t)c * NPART + k];
        q += psq [(size_t)c * NPART + k];
    }
    __shared__ float rs[256], rq[256];
    rs[tid] = s; rq[tid] = q;
    __syncthreads();
    for (int off = 128; off > 0; off >>= 1) {
        if (tid < off) { rs[tid] += rs[tid + off]; rq[tid] += rq[tid + off]; }
        __syncthreads();
    }
    const float inv_n = 1.0f / (float)(BB * NN);
    float mean = rs[0] * inv_n;
    float var  = rq[0] * inv_n - mean * mean;
    float scv = gamma[c] * rsqrtf(var + BN_EPS);
    float shv = beta[c] - mean * scv;

    #pragma unroll
    for (int it = 0; it < 2; ++it) {
        int chunk = tid + 256 * it;
        if (chunk < 288) {
            size_t base = ((size_t)(b * CCH + c)) * NN + chunk * 8;
            uint4 pv = *(const uint4*)(projb + base);
            uint4 xv = *(const uint4*)(xb + base);
            const unsigned short* pp = (const unsigned short*)&pv;
            const unsigned short* xx = (const unsigned short*)&xv;
            float4 r0, r1;
            r0.x = scv * bf2f(pp[0]) + shv + bf2f(xx[0]);
            r0.y = scv * bf2f(pp[1]) + shv + bf2f(xx[1]);
            r0.z = scv * bf2f(pp[2]) + shv + bf2f(xx[2]);
            r0.w = scv * bf2f(pp[3]) + shv + bf2f(xx[3]);
            r1.x = scv * bf2f(pp[4]) + shv + bf2f(xx[4]);
            r1.y = scv * bf2f(pp[5]) + shv + bf2f(xx[5]);
            r1.z = scv * bf2f(pp[6]) + shv + bf2f(xx[6]);
            r1.w = scv * bf2f(pp[7]) + shv + bf2f(xx[7]);
            *(float4*)(out + base) = r0;
            *(float4*)(out + base + 4) = r1;
        }
    }
}

extern "C" void kernel_launch(void* const* d_in, const int* in_sizes, int n_in,
                              void* d_out, int out_size, void* d_ws, size_t ws_size,
                              hipStream_t stream)
{
    const float* x     = (const float*)d_in[0];
    const float* qw    = (const float*)d_in[1];
    const float* kw    = (const float*)d_in[2];
    const float* vw    = (const float*)d_in[3];
    const float* pw    = (const float*)d_in[4];
    const float* pb    = (const float*)d_in[5];
    const float* gamma = (const float*)d_in[6];
    const float* beta  = (const float*)d_in[7];
    float* out = (float*)d_out;

    char* ws = (char*)d_ws;
    // Ao overlays xT (dead after K1); projb overlays Qt (dead after K2).
    unsigned short* xT = (unsigned short*)ws;                       //  9,437,184
    unsigned short* Ao = (unsigned short*)ws;                       //  overlay
    unsigned short* Wb = (unsigned short*)(ws + 9437184);           //    196,608
    unsigned short* Pb = (unsigned short*)(ws + 9633792);           //    131,072
    unsigned short* Qt = (unsigned short*)(ws + 9764864);           //  9,437,184
    unsigned short* Kt = (unsigned short*)(ws + 19202048);          //  2,359,296
    unsigned short* Vn = (unsigned short*)(ws + 21561344);          //  2,359,296
    unsigned short* projb = (unsigned short*)(ws + 9764864);        //  overlay (9.4 MB)
    float* psum  = (float*)(ws + 28639232);                         //    294,912
    float* psq   = (float*)(ws + 28934144);                         //    294,912
    unsigned short* xb = (unsigned short*)(ws + 29229056);          //  4,718,592

    prep_k<<<1792, 256, 0, stream>>>(x, qw, kw, vw, pw, xT, xb, Wb, Pb);

    dim3 g1(BB, NN / 64, 3);
    qkv_mfma_k<<<g1, 128, 0, stream>>>(Wb, xT, Qt, Kt, Vn);

    dim3 g2(BB, NN / 64, NH / 2);
    attn_k<<<g2, 512, 0, stream>>>(Qt, Kt, Vn, Ao);

    dim3 g3(BB, NN / 64, 2);
    proj_mfma_k<<<g3, 128, 0, stream>>>(Pb, Ao, pb, projb, psum, psq);

    dim3 g4(BB, CCH);
    bn_apply_k<<<g4, 256, 0, stream>>>(projb, xb, psum, psq, gamma, beta, out);
}

// Round 17
// 198.541 us; speedup vs baseline: 2.6987x; 2.6987x over previous
//
#include <hip/hip_runtime.h>
#include <hip/hip_bf16.h>
#include <math.h>

#define BB 8
#define CCH 256          // channels
#define NN 2304          // H*W
#define NH 4
#define HDIM 64
#define QKV_ROWS 384
#define BN_EPS 1e-5f
#define NTILES 36        // NN / 64
#define HTILES 18        // NTILES / 2 (key-split halves)
#define NPART 288        // BB * 36 proj blocks contributing per channel
// scale folded into q weights: 1/sqrt(64) * log2(e)  -> attention uses exp2
#define SLOG2E 0.18033688011112042f

typedef short bf16x8 __attribute__((ext_vector_type(8)));
typedef short bf16x4 __attribute__((ext_vector_type(4)));
typedef float f32x4 __attribute__((ext_vector_type(4)));

#if __has_builtin(__builtin_amdgcn_exp2f)
#define EXP2(x) __builtin_amdgcn_exp2f(x)
#else
#define EXP2(x) __expf((x) * 0.6931471805599453f)
#endif

// K=16 bf16 MFMA: A/B = 4 bf16 (2 VGPRs), C/D = 4 f32 (ISA §10).
#define MFMA16(a, b, c) __builtin_amdgcn_mfma_f32_16x16x16bf16_1k(a, b, c, 0, 0, 0)
#define MFMA32(a, b, c) __builtin_amdgcn_mfma_f32_16x16x32_bf16(a, b, c, 0, 0, 0)

__device__ __forceinline__ unsigned bfpair(float a, float b) {
    __hip_bfloat162 h = __float22bfloat162_rn(make_float2(a, b));
    return *(unsigned*)&h;
}
__device__ __forceinline__ unsigned short f2bf(float f) {
    unsigned u = __float_as_uint(f);
    u = (u + 0x7FFFu + ((u >> 16) & 1u)) >> 16;
    return (unsigned short)u;
}
__device__ __forceinline__ bf16x4 pack4(float p0, float p1, float p2, float p3) {
    union { unsigned u[2]; bf16x4 v; } x;
    x.u[0] = bfpair(p0, p1);
    x.u[1] = bfpair(p2, p3);
    return x.v;
}
__device__ __forceinline__ float bf2f(unsigned short s) {
    return __uint_as_float((unsigned)s << 16);
}

// ---------------------------------------------------------------------------
// K0: prep — x-transpose/convert (+bf16 residual copy xb) + weight convert.
// ---------------------------------------------------------------------------
__global__ __launch_bounds__(256) void prep_k(
    const float* __restrict__ x,
    const float* __restrict__ qw, const float* __restrict__ kw,
    const float* __restrict__ vw, const float* __restrict__ pw,
    unsigned short* __restrict__ xT, unsigned short* __restrict__ xb,
    unsigned short* __restrict__ Wb, unsigned short* __restrict__ Pb)
{
    const int bid = blockIdx.x;
    const int tid = threadIdx.x;
    if (bid < 1152) {
        __shared__ float sX[64][65];
        const int b  = bid / 144;
        const int rem = bid - b * 144;
        const int nb = (rem >> 2) * 64;
        const int cb = (rem & 3) * 64;

        #pragma unroll
        for (int u = 0; u < 4; ++u) {
            int c  = (tid >> 4) + 16 * u;
            int n4 = (tid & 15) * 4;
            float4 v = *(const float4*)(x + ((size_t)(b * CCH + cb + c)) * NN + nb + n4);
            sX[c][n4+0] = v.x; sX[c][n4+1] = v.y; sX[c][n4+2] = v.z; sX[c][n4+3] = v.w;
        }
        __syncthreads();

        // xT[b][n][c] (transposed)
        const int n  = tid >> 2;
        const int cg = (tid & 3) * 16;
        unsigned vals[8];
        #pragma unroll
        for (int p = 0; p < 8; ++p)
            vals[p] = bfpair(sX[cg + 2*p][n], sX[cg + 2*p + 1][n]);
        unsigned short* dst = xT + ((size_t)(b * NN + nb + n)) * CCH + cb + cg;
        *(uint4*)dst = make_uint4(vals[0], vals[1], vals[2], vals[3]);
        *(uint4*)(dst + 8) = make_uint4(vals[4], vals[5], vals[6], vals[7]);

        // xb[b][c][n] (same layout as x, bf16) — for bn_apply residual
        #pragma unroll
        for (int it = 0; it < 2; ++it) {
            int flat = tid + 256 * it;      // 0..511
            int row = flat >> 3;            // c local
            int n8  = (flat & 7) * 8;
            unsigned vv[4];
            #pragma unroll
            for (int p = 0; p < 4; ++p)
                vv[p] = bfpair(sX[row][n8 + 2*p], sX[row][n8 + 2*p + 1]);
            *(uint4*)(xb + ((size_t)(b * CCH + cb + row)) * NN + nb + n8) =
                make_uint4(vv[0], vv[1], vv[2], vv[3]);
        }
    } else {
        int idx = (bid - 1152) * 256 + tid;
        if (idx < 98304) {
            int o = idx >> 8, c = idx & 255;
            float v;
            if (o < 256)      v = qw[(size_t)o * CCH + c] * SLOG2E;
            else if (o < 320) v = kw[(size_t)(o - 256) * CCH + c];
            else              v = vw[(size_t)(o - 320) * CCH + c];
            Wb[idx] = f2bf(v);
        } else {
            int j = idx - 98304;
            if (j < 65536) Pb[j] = f2bf(pw[j]);
        }
    }
}

// ---------------------------------------------------------------------------
// K1: qkv MFMA GEMM, K-loop software-pipelined (round-11/13 verified 64x64).
// grid (8 b, 36 ntile, 3 otile), 128 thr (2 waves).
//   Qt[b][n][256] (q pre-scaled), Kt[b][n][64], Vn[b][64][n], all bf16.
// ---------------------------------------------------------------------------
__global__ __launch_bounds__(128) void qkv_mfma_k(
    const unsigned short* __restrict__ Wb, const unsigned short* __restrict__ xT,
    unsigned short* __restrict__ Qt, unsigned short* __restrict__ Kt,
    unsigned short* __restrict__ Vn)
{
    __shared__ unsigned short sE[2][64 * 72];
    const int tid = threadIdx.x;
    const int wave = tid >> 6;
    const int lane = tid & 63;
    const int quad = lane >> 4;
    const int l15  = lane & 15;
    const int b  = blockIdx.x;
    const int nb = blockIdx.y * 64;
    const int mb = blockIdx.z * 128 + wave * 64;

    const unsigned short* Ab = Wb + (size_t)(mb + l15) * CCH + quad * 8;
    const unsigned short* Bb = xT + ((size_t)(b * NN + nb + l15)) * CCH + quad * 8;

    f32x4 C[4][4] = {};
    bf16x8 aA[2][4], bB[2][4];
    #pragma unroll
    for (int i = 0; i < 4; ++i) aA[0][i] = *(const bf16x8*)(Ab + (size_t)(16*i) * CCH);
    #pragma unroll
    for (int j = 0; j < 4; ++j) bB[0][j] = *(const bf16x8*)(Bb + (size_t)(16*j) * CCH);

    #pragma unroll
    for (int kk = 0; kk < 8; ++kk) {
        const int cur = kk & 1;
        if (kk < 7) {
            const int k1 = (kk + 1) * 32;
            #pragma unroll
            for (int i = 0; i < 4; ++i) aA[cur^1][i] = *(const bf16x8*)(Ab + (size_t)(16*i) * CCH + k1);
            #pragma unroll
            for (int j = 0; j < 4; ++j) bB[cur^1][j] = *(const bf16x8*)(Bb + (size_t)(16*j) * CCH + k1);
        }
        #pragma unroll
        for (int i = 0; i < 4; ++i)
            #pragma unroll
            for (int j = 0; j < 4; ++j)
                C[i][j] = MFMA32(aA[cur][i], bB[cur][j], C[i][j]);
    }

    unsigned short* sEw = &sE[wave][0];
    if (mb < 320) {
        // Q or K: transpose to [n][o] rows
        #pragma unroll
        for (int i = 0; i < 4; ++i)
            #pragma unroll
            for (int j = 0; j < 4; ++j) {
                unsigned p01 = bfpair(C[i][j][0], C[i][j][1]);
                unsigned p23 = bfpair(C[i][j][2], C[i][j][3]);
                unsigned short* p = sEw + (16*j + l15) * 72 + 16*i + quad*4;
                *(unsigned*)p = p01;
                *(unsigned*)(p + 2) = p23;
            }
        if (mb < 256) {
            #pragma unroll
            for (int it = 0; it < 8; ++it) {
                int flat = lane + 64 * it;
                int row = flat >> 3;
                int o8  = (flat & 7) * 8;
                uint4 v = *(const uint4*)(sEw + row * 72 + o8);
                *(uint4*)(Qt + ((size_t)(b * NN + nb + row)) * CCH + mb + o8) = v;
            }
        } else {
            #pragma unroll
            for (int it = 0; it < 8; ++it) {
                int flat = lane + 64 * it;
                int row = flat >> 3;
                int o8  = (flat & 7) * 8;
                uint4 v = *(const uint4*)(sEw + row * 72 + o8);
                *(uint4*)(Kt + ((size_t)(b * NN + nb + row)) * 64 + o8) = v;
            }
        }
    } else {
        // V: [d][n] rows
        #pragma unroll
        for (int i = 0; i < 4; ++i)
            #pragma unroll
            for (int j = 0; j < 4; ++j) {
                unsigned p01 = bfpair(C[i][j][0], C[i][j][1]);
                unsigned p23 = bfpair(C[i][j][2], C[i][j][3]);
                unsigned short* p = sEw + (16*i + quad*4) * 72 + 16*j + l15;
                p[0]   = (unsigned short)p01;
                p[72]  = (unsigned short)(p01 >> 16);
                p[144] = (unsigned short)p23;
                p[216] = (unsigned short)(p23 >> 16);
            }
        #pragma unroll
        for (int it = 0; it < 8; ++it) {
            int flat = lane + 64 * it;
            int row = flat >> 3;
            int n8  = (flat & 7) * 8;
            uint4 v = *(const uint4*)(sEw + row * 72 + n8);
            *(uint4*)(Vn + ((size_t)(b * 64 + (mb - 320) + row)) * NN + nb + n8) = v;
        }
    }
}

// ---------------------------------------------------------------------------
// K2: MFMA attention — round-15 verified best (78.8 µs): DOUBLE-BUFFERED LDS,
// one barrier per K-step, XOR-swizzled pitch-64 tiles, 64 KB LDS, (512,4).
// r10+r16 lesson: do NOT raise the min-waves hint — live state (bQ/pf/O/C/bP)
// needs the 128-VGPR budget; forcing 8 waves/SIMD spills ~1.5 GB to scratch.
// ---------------------------------------------------------------------------
__global__ __launch_bounds__(512, 4) void attn_k(
    const unsigned short* __restrict__ Qt,  // [B][N][256]
    const unsigned short* __restrict__ Kt,  // [B][N][64]
    const unsigned short* __restrict__ Vn,  // [B][64][N]
    unsigned short* __restrict__ Ao)        // [B][N][256]
{
    // [2 phase][4 buf: Kh0,Vh0,Kh1,Vh1][64 rows][64] bf16, XOR-swizzled
    __shared__ __align__(16) unsigned short sKV[2 * 4 * 64 * 64];   // 65536 B

    const int tid   = threadIdx.x;
    const int wave  = tid >> 6;
    const int lane  = tid & 63;
    const int quad  = lane >> 4;
    const int l15   = lane & 15;
    const int qslot = wave & 1;
    const int kh    = (wave >> 1) & 1;
    const int hloc  = wave >> 2;
    const int qoff  = qslot * 32;
    const int b     = blockIdx.x;
    const int nb    = blockIdx.y * 64;
    const int head  = blockIdx.z * 2 + hloc;

    const bf16x4 vone = {(short)0x3F80, (short)0x3F80, (short)0x3F80, (short)0x3F80};

    // Q fragments (B-operand for S^T): B[n=query=l15][k=d=quad*8+j]
    bf16x8 bQ[2][2];
    const unsigned short* QtB = Qt + ((size_t)(b * NN + nb + qoff + l15)) * CCH + head * 64 + quad * 8;
    #pragma unroll
    for (int qt = 0; qt < 2; ++qt)
        #pragma unroll
        for (int s = 0; s < 2; ++s)
            bQ[qt][s] = *(const bf16x8*)(QtB + (size_t)(16*qt) * CCH + s * 32);

    // staging geometry: 512 thr x 1 chunk per buffer; swizzled write column
    const int srow = tid >> 3;
    const int swch = ((tid & 7) ^ (srow & 7)) * 8;
    const int sgc8 = (tid & 7) * 8;          // global (unswizzled) column

    bf16x8 pf[4];
    #pragma unroll
    for (int u = 0; u < 4; ++u) {            // step 0
        const int keys0 = (u >> 1) * HTILES * 64;
        if ((u & 1) == 0)
            pf[u] = *(const bf16x8*)(Kt + ((size_t)(b * NN + keys0 + srow)) * 64 + sgc8);
        else
            pf[u] = *(const bf16x8*)(Vn + ((size_t)(b * 64 + srow)) * NN + keys0 + sgc8);
    }
    #pragma unroll
    for (int u = 0; u < 4; ++u)              // write step 0 -> phase 0
        *(bf16x8*)(sKV + u * 4096 + srow * 64 + swch) = pf[u];
    #pragma unroll
    for (int u = 0; u < 4; ++u) {            // prefetch step 1
        const int keys0 = ((u >> 1) * HTILES + 1) * 64;
        if ((u & 1) == 0)
            pf[u] = *(const bf16x8*)(Kt + ((size_t)(b * NN + keys0 + srow)) * 64 + sgc8);
        else
            pf[u] = *(const bf16x8*)(Vn + ((size_t)(b * 64 + srow)) * NN + keys0 + sgc8);
    }

    f32x4 O[4][2] = {};          // O^T[d-tile jd][q-tile qt]
    f32x4 dacc[2] = {};          // softmax denominators via ones-MFMA

    for (int step = 0; step < HTILES; ++step) {
        const int cur = step & 1;
        __syncthreads();   // buf[cur] writes visible; all reads of buf[cur^1] done

        // write step+1 tiles into the other phase (overlaps compute below)
        if (step + 1 < HTILES) {
            #pragma unroll
            for (int u = 0; u < 4; ++u)
                *(bf16x8*)(sKV + (cur ^ 1) * 16384 + u * 4096 + srow * 64 + swch) = pf[u];
        }
        // prefetch step+2 (consumed at next iteration's write — full step slack)
        if (step + 2 < HTILES) {
            #pragma unroll
            for (int u = 0; u < 4; ++u) {
                const int keys0 = ((u >> 1) * HTILES + step + 2) * 64;
                if ((u & 1) == 0)
                    pf[u] = *(const bf16x8*)(Kt + ((size_t)(b * NN + keys0 + srow)) * 64 + sgc8);
                else
                    pf[u] = *(const bf16x8*)(Vn + ((size_t)(b * 64 + srow)) * NN + keys0 + sgc8);
            }
        }

        const unsigned short* sKb = sKV + cur * 16384 + kh * 2 * 4096;
        const unsigned short* sVb = sKb + 4096;

        // S^T[key][q]: swizzled aK reads
        f32x4 C[4][2] = {};
        #pragma unroll
        for (int s = 0; s < 2; ++s)
            #pragma unroll
            for (int kt = 0; kt < 4; ++kt) {
                const int row = 16*kt + l15;
                const int chsw = ((s*4 + quad) ^ (row & 7)) * 8;
                bf16x8 aK = *(const bf16x8*)(sKb + row * 64 + chsw);
                C[kt][0] = MFMA32(aK, bQ[0][s], C[kt][0]);
                C[kt][1] = MFMA32(aK, bQ[1][s], C[kt][1]);
            }

        // P^T = exp2(S^T) -> bf16 B-fragments
        bf16x4 bP[4][2];
        #pragma unroll
        for (int kt = 0; kt < 4; ++kt)
            #pragma unroll
            for (int qt = 0; qt < 2; ++qt)
                bP[kt][qt] = pack4(EXP2(C[kt][qt][0]), EXP2(C[kt][qt][1]),
                                   EXP2(C[kt][qt][2]), EXP2(C[kt][qt][3]));

        // denominators on the matrix pipe
        #pragma unroll
        for (int kt = 0; kt < 4; ++kt) {
            dacc[0] = MFMA16(vone, bP[kt][0], dacc[0]);
            dacc[1] = MFMA16(vone, bP[kt][1], dacc[1]);
        }

        // O^T += V . P^T (swizzled aV reads)
        #pragma unroll
        for (int jd = 0; jd < 4; ++jd)
            #pragma unroll
            for (int kt = 0; kt < 4; ++kt) {
                const int row = 16*jd + l15;
                const int chsw = ((2*kt + (quad >> 1)) ^ (row & 7)) * 8 + (quad & 1) * 4;
                bf16x4 aV = *(const bf16x4*)(sVb + row * 64 + chsw);
                O[jd][0] = MFMA16(aV, bP[kt][0], O[jd][0]);
                O[jd][1] = MFMA16(aV, bP[kt][1], O[jd][1]);
            }
    }
    __syncthreads();   // all K/V reads done before scratch overlay

    // merge key halves: kh=1 waves dump O + dacc to LDS scratch (floats)
    float* sc = (float*)sKV;   // 4 groups x 64 lanes x 36 floats = 36864 B
    const int base = (hloc * 2 + qslot) * 2304 + lane * 36;
    if (kh == 1) {
        #pragma unroll
        for (int jd = 0; jd < 4; ++jd)
            #pragma unroll
            for (int qt = 0; qt < 2; ++qt)
                *(f32x4*)(sc + base + jd * 8 + qt * 4) = O[jd][qt];
        sc[base + 32] = dacc[0][0];
        sc[base + 33] = dacc[1][0];
    }
    __syncthreads();
    float rinv[2] = {0.f, 0.f};
    if (kh == 0) {
        #pragma unroll
        for (int jd = 0; jd < 4; ++jd)
            #pragma unroll
            for (int qt = 0; qt < 2; ++qt)
                O[jd][qt] += *(const f32x4*)(sc + base + jd * 8 + qt * 4);
        rinv[0] = 1.0f / (dacc[0][0] + sc[base + 32]);
        rinv[1] = 1.0f / (dacc[1][0] + sc[base + 33]);
    }
    __syncthreads();   // all sc reads done before sT overlay

    unsigned short* sT = (unsigned short*)sKV;   // [2 hloc][64 n][72]
    if (kh == 0) {
        #pragma unroll
        for (int qt = 0; qt < 2; ++qt)
            #pragma unroll
            for (int jd = 0; jd < 4; ++jd) {
                unsigned lo = bfpair(O[jd][qt][0] * rinv[qt], O[jd][qt][1] * rinv[qt]);
                unsigned hi = bfpair(O[jd][qt][2] * rinv[qt], O[jd][qt][3] * rinv[qt]);
                *(uint2*)(sT + (hloc * 64 + qoff + 16*qt + l15) * 72 + 16*jd + quad*4) = make_uint2(lo, hi);
            }
    }
    __syncthreads();

    // coalesced writeout: 2 heads x 64 rows x 64 channels = 1024 uint4 chunks
    #pragma unroll
    for (int it = 0; it < 2; ++it) {
        int flat = tid + 512 * it;          // 0..1023
        int hh   = flat >> 9;
        int row  = (flat >> 3) & 63;
        int c8   = (flat & 7) * 8;
        uint4 v = *(const uint4*)(sT + (hh * 64 + row) * 72 + c8);
        *(uint4*)(Ao + ((size_t)(b * NN + nb + row)) * CCH + (blockIdx.z * 2 + hh) * 64 + c8) = v;
    }
}

// ---------------------------------------------------------------------------
// K3: proj MFMA GEMM (64x64 pipelined) + per-block BN partials.
// projb[b][c][n] (bf16) = sum_o Pb[c][o]*Ao[b][n][o]+pb[c]
// grid (8 b, 36 ntile, 2 ctile), 128 thr (2 waves).
// ---------------------------------------------------------------------------
__global__ __launch_bounds__(128) void proj_mfma_k(
    const unsigned short* __restrict__ Pb, const unsigned short* __restrict__ Ao,
    const float* __restrict__ pb, unsigned short* __restrict__ projb,
    float* __restrict__ psum, float* __restrict__ psq)
{
    __shared__ unsigned short sE[2][64 * 72];
    const int tid = threadIdx.x;
    const int wave = tid >> 6;
    const int lane = tid & 63;
    const int quad = lane >> 4;
    const int l15  = lane & 15;
    const int b  = blockIdx.x;
    const int nb = blockIdx.y * 64;
    const int mb = blockIdx.z * 128 + wave * 64;
    const int part = b * NTILES + blockIdx.y;   // 0..287

    const unsigned short* Ab = Pb + (size_t)(mb + l15) * CCH + quad * 8;
    const unsigned short* Bb = Ao + ((size_t)(b * NN + nb + l15)) * CCH + quad * 8;

    f32x4 C[4][4] = {};
    bf16x8 aA[2][4], bB[2][4];
    #pragma unroll
    for (int i = 0; i < 4; ++i) aA[0][i] = *(const bf16x8*)(Ab + (size_t)(16*i) * CCH);
    #pragma unroll
    for (int j = 0; j < 4; ++j) bB[0][j] = *(const bf16x8*)(Bb + (size_t)(16*j) * CCH);

    #pragma unroll
    for (int kk = 0; kk < 8; ++kk) {
        const int cur = kk & 1;
        if (kk < 7) {
            const int k1 = (kk + 1) * 32;
            #pragma unroll
            for (int i = 0; i < 4; ++i) aA[cur^1][i] = *(const bf16x8*)(Ab + (size_t)(16*i) * CCH + k1);
            #pragma unroll
            for (int j = 0; j < 4; ++j) bB[cur^1][j] = *(const bf16x8*)(Bb + (size_t)(16*j) * CCH + k1);
        }
        #pragma unroll
        for (int i = 0; i < 4; ++i)
            #pragma unroll
            for (int j = 0; j < 4; ++j)
                C[i][j] = MFMA32(aA[cur][i], bB[cur][j], C[i][j]);
    }

    unsigned short* sEw = &sE[wave][0];
    #pragma unroll
    for (int i = 0; i < 4; ++i) {
        #pragma unroll
        for (int r = 0; r < 4; ++r) {
            const int ch = mb + 16*i + quad*4 + r;
            const float bias = pb[ch];
            float v0 = C[i][0][r] + bias, v1 = C[i][1][r] + bias;
            float v2 = C[i][2][r] + bias, v3 = C[i][3][r] + bias;
            C[i][0][r] = v0; C[i][1][r] = v1; C[i][2][r] = v2; C[i][3][r] = v3;
            float rs = (v0 + v1) + (v2 + v3);
            float rq = (v0*v0 + v1*v1) + (v2*v2 + v3*v3);
            rs += __shfl_xor(rs, 1); rq += __shfl_xor(rq, 1);
            rs += __shfl_xor(rs, 2); rq += __shfl_xor(rq, 2);
            rs += __shfl_xor(rs, 4); rq += __shfl_xor(rq, 4);
            rs += __shfl_xor(rs, 8); rq += __shfl_xor(rq, 8);
            if (l15 == 0) {
                psum[(size_t)ch * NPART + part] = rs;
                psq [(size_t)ch * NPART + part] = rq;
            }
        }
    }

    // bf16 output via LDS transpose: rows = c_local, cols = n
    #pragma unroll
    for (int i = 0; i < 4; ++i)
        #pragma unroll
        for (int j = 0; j < 4; ++j) {
            unsigned p01 = bfpair(C[i][j][0], C[i][j][1]);
            unsigned p23 = bfpair(C[i][j][2], C[i][j][3]);
            unsigned short* p = sEw + (16*i + quad*4) * 72 + 16*j + l15;
            p[0]   = (unsigned short)p01;
            p[72]  = (unsigned short)(p01 >> 16);
            p[144] = (unsigned short)p23;
            p[216] = (unsigned short)(p23 >> 16);
        }
    #pragma unroll
    for (int it = 0; it < 8; ++it) {
        int flat = lane + 64 * it;
        int row = flat >> 3;                // c local
        int n8  = (flat & 7) * 8;
        uint4 v = *(const uint4*)(sEw + row * 72 + n8);
        *(uint4*)(projb + ((size_t)(b * CCH + mb + row)) * NN + nb + n8) = v;
    }
}

// ---------------------------------------------------------------------------
// K4: fused BN finalize + apply. grid (8 b, 256 c), 256 thr.
// out = scale[c]*projb + shift[c] + xb   (projb, xb bf16; out fp32)
// ---------------------------------------------------------------------------
__global__ __launch_bounds__(256) void bn_apply_k(
    const unsigned short* __restrict__ projb, const unsigned short* __restrict__ xb,
    const float* __restrict__ psum, const float* __restrict__ psq,
    const float* __restrict__ gamma, const float* __restrict__ beta,
    float* __restrict__ out)
{
    const int tid = threadIdx.x;
    const int b = blockIdx.x;
    const int c = blockIdx.y;

    float s = 0.f, q = 0.f;
    for (int k = tid; k < NPART; k += 256) {
        s += psum[(size_t)c * NPART + k];
        q += psq [(size_t)c * NPART + k];
    }
    __shared__ float rs[256], rq[256];
    rs[tid] = s; rq[tid] = q;
    __syncthreads();
    for (int off = 128; off > 0; off >>= 1) {
        if (tid < off) { rs[tid] += rs[tid + off]; rq[tid] += rq[tid + off]; }
        __syncthreads();
    }
    const float inv_n = 1.0f / (float)(BB * NN);
    float mean = rs[0] * inv_n;
    float var  = rq[0] * inv_n - mean * mean;
    float scv = gamma[c] * rsqrtf(var + BN_EPS);
    float shv = beta[c] - mean * scv;

    #pragma unroll
    for (int it = 0; it < 2; ++it) {
        int chunk = tid + 256 * it;
        if (chunk < 288) {
            size_t base = ((size_t)(b * CCH + c)) * NN + chunk * 8;
            uint4 pv = *(const uint4*)(projb + base);
            uint4 xv = *(const uint4*)(xb + base);
            const unsigned short* pp = (const unsigned short*)&pv;
            const unsigned short* xx = (const unsigned short*)&xv;
            float4 r0, r1;
            r0.x = scv * bf2f(pp[0]) + shv + bf2f(xx[0]);
            r0.y = scv * bf2f(pp[1]) + shv + bf2f(xx[1]);
            r0.z = scv * bf2f(pp[2]) + shv + bf2f(xx[2]);
            r0.w = scv * bf2f(pp[3]) + shv + bf2f(xx[3]);
            r1.x = scv * bf2f(pp[4]) + shv + bf2f(xx[4]);
            r1.y = scv * bf2f(pp[5]) + shv + bf2f(xx[5]);
            r1.z = scv * bf2f(pp[6]) + shv + bf2f(xx[6]);
            r1.w = scv * bf2f(pp[7]) + shv + bf2f(xx[7]);
            *(float4*)(out + base) = r0;
            *(float4*)(out + base + 4) = r1;
        }
    }
}

extern "C" void kernel_launch(void* const* d_in, const int* in_sizes, int n_in,
                              void* d_out, int out_size, void* d_ws, size_t ws_size,
                              hipStream_t stream)
{
    const float* x     = (const float*)d_in[0];
    const float* qw    = (const float*)d_in[1];
    const float* kw    = (const float*)d_in[2];
    const float* vw    = (const float*)d_in[3];
    const float* pw    = (const float*)d_in[4];
    const float* pb    = (const float*)d_in[5];
    const float* gamma = (const float*)d_in[6];
    const float* beta  = (const float*)d_in[7];
    float* out = (float*)d_out;

    char* ws = (char*)d_ws;
    // Ao overlays xT (dead after K1); projb overlays Qt (dead after K2).
    unsigned short* xT = (unsigned short*)ws;                       //  9,437,184
    unsigned short* Ao = (unsigned short*)ws;                       //  overlay
    unsigned short* Wb = (unsigned short*)(ws + 9437184);           //    196,608
    unsigned short* Pb = (unsigned short*)(ws + 9633792);           //    131,072
    unsigned short* Qt = (unsigned short*)(ws + 9764864);           //  9,437,184
    unsigned short* Kt = (unsigned short*)(ws + 19202048);          //  2,359,296
    unsigned short* Vn = (unsigned short*)(ws + 21561344);          //  2,359,296
    unsigned short* projb = (unsigned short*)(ws + 9764864);        //  overlay (9.4 MB)
    float* psum  = (float*)(ws + 28639232);                         //    294,912
    float* psq   = (float*)(ws + 28934144);                         //    294,912
    unsigned short* xb = (unsigned short*)(ws + 29229056);          //  4,718,592

    prep_k<<<1792, 256, 0, stream>>>(x, qw, kw, vw, pw, xT, xb, Wb, Pb);

    dim3 g1(BB, NN / 64, 3);
    qkv_mfma_k<<<g1, 128, 0, stream>>>(Wb, xT, Qt, Kt, Vn);

    dim3 g2(BB, NN / 64, NH / 2);
    attn_k<<<g2, 512, 0, stream>>>(Qt, Kt, Vn, Ao);

    dim3 g3(BB, NN / 64, 2);
    proj_mfma_k<<<g3, 128, 0, stream>>>(Pb, Ao, pb, projb, psum, psq);

    dim3 g4(BB, CCH);
    bn_apply_k<<<g4, 256, 0, stream>>>(projb, xb, psum, psq, gamma, beta, out);
}